// Round 10
// baseline (117.230 us; speedup 1.0000x reference)
//
#include <hip/hip_runtime.h>

typedef __bf16 bf16x8 __attribute__((ext_vector_type(8)));
typedef float  f32x4  __attribute__((ext_vector_type(4)));

#define IC    256
#define OC    256
#define Hh    64
#define Ww    64
#define Bb    16
#define DLEN  512
#define KKTOT 2304        // IC*9
#define HP    66          // padded spatial
#define NT    72          // K tiles of 32
#define MODSCALE 0.0625f                 // sqrt(2/512)
#define WSCALE   0.029462782549439484f   // sqrt(2/2304)

// workspace layout (bytes)
#define XT_ELEMS  (Bb*HP*HP*IC)          // 17,842,176 bf16
#define XT_BYTES  (XT_ELEMS*2)           // 35,684,352
#define WMAT_OFF  XT_BYTES
#define WMAT_BYTES (OC*KKTOT*2)          // 1,179,648
#define S_OFF     (WMAT_OFF + WMAT_BYTES)

typedef const __attribute__((address_space(1))) unsigned int* gptr_t;
typedef __attribute__((address_space(3))) unsigned int* lptr_t;

__device__ __forceinline__ void gl2lds16(const void* g, void* l) {
  __builtin_amdgcn_global_load_lds((gptr_t)g, (lptr_t)l, 16, 0, 0);
}

// ---------------- s[b][ic] = sum_dl style[b][dl]*mod_weight[ic][dl]*MODSCALE
__global__ void k_style(const float* __restrict__ style,
                        const float* __restrict__ mw,
                        float* __restrict__ s_out) {
  __shared__ float st[DLEN];
  const int b = blockIdx.x, t = threadIdx.x;
  st[t]       = style[b*DLEN + t];
  st[t + 256] = style[b*DLEN + t + 256];
  __syncthreads();
  const float4* mwr = (const float4*)(mw + (long)t*DLEN);
  float acc = 0.f;
  #pragma unroll 4
  for (int d = 0; d < DLEN/4; ++d) {
    float4 v = mwr[d];
    acc += v.x*st[d*4] + v.y*st[d*4+1] + v.z*st[d*4+2] + v.w*st[d*4+3];
  }
  s_out[b*IC + t] = acc * MODSCALE;
}

// ---------------- wmat[oc][(kh*3+kw)*256+ic] = bf16(w * WSCALE * demod[oc])
__global__ void k_wmat(const float* __restrict__ wt, __bf16* __restrict__ wmat) {
  const int oc = blockIdx.x, t = threadIdx.x;   // t = ic
  float w9[9];
  const float* p = wt + ((long)oc*IC + t)*9;
  float ss = 0.f;
  #pragma unroll
  for (int r = 0; r < 9; ++r) { w9[r] = p[r]; ss += w9[r]*w9[r]; }
  #pragma unroll
  for (int off = 32; off; off >>= 1) ss += __shfl_down(ss, off, 64);
  __shared__ float red[4];
  if ((t & 63) == 0) red[t >> 6] = ss;
  __syncthreads();
  float total = red[0] + red[1] + red[2] + red[3];
  float dm = WSCALE / sqrtf(total + 1e-8f);
  #pragma unroll
  for (int r = 0; r < 9; ++r)
    wmat[oc*KKTOT + r*IC + t] = (__bf16)(w9[r] * dm);
}

// ---------------- xt[b][y+1][x+1][ic] = bf16(image[b][ic][y][x] * s[b][ic]) (NHWC, padded)
// blocks >= Bb*256 zero the halo of batch (blockIdx.x - Bb*256); writes disjoint.
__global__ void k_xmod(const float* __restrict__ img,
                       const float* __restrict__ s,
                       __bf16* __restrict__ xt) {
  const int t = threadIdx.x;
  if (blockIdx.x >= Bb*256) {
    const int b = blockIdx.x - Bb*256;
    uint4* base = (uint4*)(xt + (long)b*HP*HP*IC);
    const uint4 z = {0u,0u,0u,0u};
    for (int i = t; i < 2112; i += 256) { base[i] = z; base[137280 + i] = z; }
    for (int i = t; i < 64*32; i += 256) {
      int y = 1 + (i >> 5), c = i & 31;
      base[y*2112 + c] = z;
      base[y*2112 + 2080 + c] = z;
    }
    return;
  }
  __shared__ float tile[64][69];
  const int b   = blockIdx.x >> 8;
  const int rem = blockIdx.x & 255;
  const int y   = rem >> 2;          // source row 0..63
  const int ic0 = (rem & 3) << 6;    // ic block of 64
  #pragma unroll
  for (int r = 0; r < 4; ++r) {
    int seg = r*256 + t;
    int i   = seg >> 4;              // ic offset 0..63
    int x0  = (seg & 15) * 4;
    float4 v = *(const float4*)(img + (((long)(b*IC + ic0 + i)*Hh + y)*Ww + x0));
    float sv = s[b*IC + ic0 + i];
    tile[i][x0+0] = v.x*sv; tile[i][x0+1] = v.y*sv;
    tile[i][x0+2] = v.z*sv; tile[i][x0+3] = v.w*sv;
  }
  __syncthreads();
  const int x  = t >> 2;
  const int j0 = (t & 3) << 4;
  bf16x8 o0, o1;
  #pragma unroll
  for (int e = 0; e < 8; ++e) o0[e] = (__bf16)tile[j0 + e][x];
  #pragma unroll
  for (int e = 0; e < 8; ++e) o1[e] = (__bf16)tile[j0 + 8 + e][x];
  __bf16* dst = xt + (((long)(b*HP + y + 1)*HP + (x + 1))*IC + ic0 + j0);
  ((bf16x8*)dst)[0] = o0;
  ((bf16x8*)dst)[1] = o1;
}

// ---------------- 256(oc) x 128(hw) x BK=32 implicit-GEMM conv, 2 blocks/CU.
// LDS/block 48KB (A 16K + B 8K, double-buffered). 4 waves, wave = 128x64.
// Single __syncthreads per K-tile; cross-BLOCK wave overlap (m114) hides the
// barrier/drain windows that a single resident block cannot.
// 64B LDS rows; bank-balance XOR: 16B-chunk ^= (row>>1)&3, both sides.
__global__ __launch_bounds__(256, 2) void k_conv(const __bf16* __restrict__ wmat,
                                                 const __bf16* __restrict__ xt,
                                                 float* __restrict__ out) {
  __shared__ __attribute__((aligned(128))) char ldsc[49152]; // p*24576: A 16K | B 8K
  const int tid  = threadIdx.x;
  const int lane = tid & 63;
  const int wv   = tid >> 6;           // 0..3
  const int wr   = wv >> 1;            // 0..1 (oc half: 128 rows)
  const int wc   = wv & 1;             // 0..1 (hw half: 64 cols)

  // XCD remap: xcd = bi&7 handles batches {2*xcd, 2*xcd+1}
  const int bi     = blockIdx.x;
  const int idx    = bi >> 3;                       // 0..63
  const int b      = ((bi & 7) << 1) | (idx >> 5);
  const int hwBase = (idx & 31) << 7;               // 32 hw-tiles of 128
  const int y0     = hwBase >> 6;                   // 2 spatial rows per tile

  // ---- staging precompute: A 4 calls, B 2 calls (16B per lane per call)
  long aOff[4]; unsigned aDst[4];
  #pragma unroll
  for (int c = 0; c < 4; ++c) {
    int p16  = c*256 + wv*64 + lane;
    int row  = p16 >> 2;
    int ch   = (p16 & 3) ^ ((row >> 1) & 3);
    aOff[c]  = (long)row*KKTOT + ch*8;
    aDst[c]  = c*4096 + (unsigned)(wv << 10);
  }
  long bOff[2]; unsigned bDst[2];
  #pragma unroll
  for (int c = 0; c < 2; ++c) {
    int p16  = c*256 + wv*64 + lane;
    int row  = p16 >> 2;                            // 0..127 (hw within tile)
    int ch   = (p16 & 3) ^ ((row >> 1) & 3);
    bOff[c]  = ((long)(b*HP + y0 + (row >> 6))*HP + (row & 63))*IC + ch*8;
    bDst[c]  = 16384u + c*4096 + (unsigned)(wv << 10);
  }

#define STAGE(tt) do {                                                   \
    char* base_ = ldsc + ((tt)&1)*24576;                                 \
    int pos_ = (tt) >> 3, kh_ = pos_/3, kw_ = pos_ - kh_*3;              \
    long sa_ = (long)(tt)*32;                                            \
    long sb_ = (long)((kh_*HP + kw_)*IC + ((tt)&7)*32);                  \
    gl2lds16(wmat + aOff[0] + sa_, base_ + aDst[0]);                     \
    gl2lds16(wmat + aOff[1] + sa_, base_ + aDst[1]);                     \
    gl2lds16(wmat + aOff[2] + sa_, base_ + aDst[2]);                     \
    gl2lds16(wmat + aOff[3] + sa_, base_ + aDst[3]);                     \
    gl2lds16(xt + bOff[0] + sb_, base_ + bDst[0]);                       \
    gl2lds16(xt + bOff[1] + sb_, base_ + bDst[1]);                       \
  } while (0)

  // ---- frag-read bases (chunk XOR constant per thread: (m*16)>>1 ≡ 0 mod 4)
  const int rA0  = wr*128 + (lane & 15);
  const int rB0  = wc*64  + (lane & 15);
  const unsigned chRA = ((unsigned)((lane >> 4) ^ ((rA0 >> 1) & 3))) << 4;
  const unsigned chRB = ((unsigned)((lane >> 4) ^ ((rB0 >> 1) & 3))) << 4;

  f32x4 acc[8][4] = {};
  bf16x8 afA[4], afB[4], bfr[4];

  // ---- prologue
  STAGE(0);
  __syncthreads();

  for (int t = 0; t < NT; ++t) {
    char* base = ldsc + (t & 1)*24576;
    const char* Af = base + rA0*64 + chRA;
    const char* Bf = base + 16384 + rB0*64 + chRB;
    #pragma unroll
    for (int n = 0; n < 4; ++n) bfr[n] = *(const bf16x8*)(Bf + n*1024);
    #pragma unroll
    for (int m = 0; m < 4; ++m) afA[m] = *(const bf16x8*)(Af + m*1024);
    #pragma unroll
    for (int m = 0; m < 4; ++m) afB[m] = *(const bf16x8*)(Af + 4096 + m*1024);

    if (t < NT-1) STAGE(t+1);

    __builtin_amdgcn_s_setprio(1);
    #pragma unroll
    for (int m = 0; m < 4; ++m)
      #pragma unroll
      for (int n = 0; n < 4; ++n)
        acc[m][n] = __builtin_amdgcn_mfma_f32_16x16x32_bf16(afA[m], bfr[n], acc[m][n], 0, 0, 0);
    #pragma unroll
    for (int m = 0; m < 4; ++m)
      #pragma unroll
      for (int n = 0; n < 4; ++n)
        acc[4+m][n] = __builtin_amdgcn_mfma_f32_16x16x32_bf16(afB[m], bfr[n], acc[4+m][n], 0, 0, 0);
    __builtin_amdgcn_s_setprio(0);

    __syncthreads();
  }

  // ---- epilogue: f32 stores, 16-lane 64B segments
  float* outb = out + (((long)b*OC + wr*128 + ((lane >> 4) << 2))*(Hh*Ww))
                    + hwBase + wc*64 + (lane & 15);
  #pragma unroll
  for (int m = 0; m < 8; ++m) {
    const int rowOff = (m & 3)*16 + (m >> 2)*64;
    #pragma unroll
    for (int n = 0; n < 4; ++n)
      #pragma unroll
      for (int j = 0; j < 4; ++j)
        outb[((long)(rowOff + j))*(Hh*Ww) + n*16] = acc[m][n][j];
  }
}

extern "C" void kernel_launch(void* const* d_in, const int* in_sizes, int n_in,
                              void* d_out, int out_size, void* d_ws, size_t ws_size,
                              hipStream_t stream) {
  const float* image = (const float*)d_in[0];
  const float* style = (const float*)d_in[1];
  const float* weight= (const float*)d_in[2];
  const float* modw  = (const float*)d_in[3];
  float* out = (float*)d_out;

  char* ws = (char*)d_ws;
  __bf16* xt   = (__bf16*)ws;
  __bf16* wmat = (__bf16*)(ws + WMAT_OFF);
  float*  sbuf = (float*)(ws + S_OFF);

  k_style<<<Bb, 256, 0, stream>>>(style, modw, sbuf);
  k_wmat<<<OC, 256, 0, stream>>>(weight, wmat);
  k_xmod<<<Bb*256 + Bb, 256, 0, stream>>>(image, sbuf, xt);
  k_conv<<<512, 256, 0, stream>>>(wmat, xt, out);
}

// Round 11
// 105.826 us; speedup vs baseline: 1.1078x; 1.1078x over previous
//
#include <hip/hip_runtime.h>

typedef __bf16 bf16x8 __attribute__((ext_vector_type(8)));
typedef float  f32x4  __attribute__((ext_vector_type(4)));

#define IC    256
#define OC    256
#define Hh    64
#define Ww    64
#define Bb    16
#define DLEN  512
#define KKTOT 2304        // IC*9
#define HP    66          // padded spatial
#define MODSCALE 0.0625f                 // sqrt(2/512)
#define WSCALE   0.029462782549439484f   // sqrt(2/2304)

// workspace layout (bytes)
#define XT_ELEMS  (Bb*HP*HP*IC)          // 17,842,176 bf16
#define XT_BYTES  (XT_ELEMS*2)           // 35,684,352
#define WMAT_OFF  XT_BYTES
#define WMAT_BYTES (OC*KKTOT*2)          // 1,179,648
#define S_OFF     (WMAT_OFF + WMAT_BYTES)

typedef const __attribute__((address_space(1))) unsigned int* gptr_t;
typedef __attribute__((address_space(3))) unsigned int* lptr_t;

__device__ __forceinline__ void gl2lds16(const void* g, void* l) {
  __builtin_amdgcn_global_load_lds((gptr_t)g, (lptr_t)l, 16, 0, 0);
}

// ---------------- merged prep: blocks 0..255 = wmat(+demod), 256..271 = style
__global__ void k_prep(const float* __restrict__ wt,
                       const float* __restrict__ style,
                       const float* __restrict__ mw,
                       __bf16* __restrict__ wmat,
                       float* __restrict__ s_out) {
  const int t = threadIdx.x;
  if (blockIdx.x >= 256) {
    // ---- style: s[b][ic] = sum_dl style[b][dl]*mod_weight[ic][dl]*MODSCALE
    const int b = blockIdx.x - 256;
    __shared__ float st[DLEN];
    st[t]       = style[b*DLEN + t];
    st[t + 256] = style[b*DLEN + t + 256];
    __syncthreads();
    const float4* mwr = (const float4*)(mw + (long)t*DLEN);
    float acc = 0.f;
    #pragma unroll 4
    for (int d = 0; d < DLEN/4; ++d) {
      float4 v = mwr[d];
      acc += v.x*st[d*4] + v.y*st[d*4+1] + v.z*st[d*4+2] + v.w*st[d*4+3];
    }
    s_out[b*IC + t] = acc * MODSCALE;
    return;
  }
  // ---- wmat[oc][(kh*3+kw)*256+ic] = bf16(w * WSCALE * demod[oc])
  const int oc = blockIdx.x;
  float w9[9];
  const float* p = wt + ((long)oc*IC + t)*9;
  float ss = 0.f;
  #pragma unroll
  for (int r = 0; r < 9; ++r) { w9[r] = p[r]; ss += w9[r]*w9[r]; }
  #pragma unroll
  for (int off = 32; off; off >>= 1) ss += __shfl_down(ss, off, 64);
  __shared__ float red[4];
  if ((t & 63) == 0) red[t >> 6] = ss;
  __syncthreads();
  float total = red[0] + red[1] + red[2] + red[3];
  float dm = WSCALE / sqrtf(total + 1e-8f);
  #pragma unroll
  for (int r = 0; r < 9; ++r)
    wmat[oc*KKTOT + r*IC + t] = (__bf16)(w9[r] * dm);
}

// ---------------- xt[b][y+1][x+1][ic] = bf16(image[b][ic][y][x] * s[b][ic]) (NHWC, padded)
// blocks >= Bb*256 zero the halo of batch (blockIdx.x - Bb*256); writes disjoint.
__global__ void k_xmod(const float* __restrict__ img,
                       const float* __restrict__ s,
                       __bf16* __restrict__ xt) {
  const int t = threadIdx.x;
  if (blockIdx.x >= Bb*256) {
    const int b = blockIdx.x - Bb*256;
    uint4* base = (uint4*)(xt + (long)b*HP*HP*IC);
    const uint4 z = {0u,0u,0u,0u};
    for (int i = t; i < 2112; i += 256) { base[i] = z; base[137280 + i] = z; }
    for (int i = t; i < 64*32; i += 256) {
      int y = 1 + (i >> 5), c = i & 31;
      base[y*2112 + c] = z;
      base[y*2112 + 2080 + c] = z;
    }
    return;
  }
  __shared__ float tile[64][69];
  const int b   = blockIdx.x >> 8;
  const int rem = blockIdx.x & 255;
  const int y   = rem >> 2;          // source row 0..63
  const int ic0 = (rem & 3) << 6;    // ic block of 64
  #pragma unroll
  for (int r = 0; r < 4; ++r) {
    int seg = r*256 + t;
    int i   = seg >> 4;              // ic offset 0..63
    int x0  = (seg & 15) * 4;
    float4 v = *(const float4*)(img + (((long)(b*IC + ic0 + i)*Hh + y)*Ww + x0));
    float sv = s[b*IC + ic0 + i];
    tile[i][x0+0] = v.x*sv; tile[i][x0+1] = v.y*sv;
    tile[i][x0+2] = v.z*sv; tile[i][x0+3] = v.w*sv;
  }
  __syncthreads();
  const int x  = t >> 2;
  const int j0 = (t & 3) << 4;
  bf16x8 o0, o1;
  #pragma unroll
  for (int e = 0; e < 8; ++e) o0[e] = (__bf16)tile[j0 + e][x];
  #pragma unroll
  for (int e = 0; e < 8; ++e) o1[e] = (__bf16)tile[j0 + 8 + e][x];
  __bf16* dst = xt + (((long)(b*HP + y + 1)*HP + (x + 1))*IC + ic0 + j0);
  ((bf16x8*)dst)[0] = o0;
  ((bf16x8*)dst)[1] = o1;
}

// ---------------- 256x256x64 implicit-GEMM conv (r8 structure, proven 75us)
// single __syncthreads per K-tile, ping-pong A-frag sets, + T19
// sched_group_barrier in q0/q1 clusters to interleave the q2/q3 ds_reads
// into the MFMA stream at compile time.
__global__ __launch_bounds__(512, 2) void k_conv(const __bf16* __restrict__ wmat,
                                                 const __bf16* __restrict__ xt,
                                                 float* __restrict__ out) {
  __shared__ __attribute__((aligned(128))) char ldsc[131072]; // 2 bufs x (A 32K | B 32K)
  const int tid  = threadIdx.x;
  const int lane = tid & 63;
  const int wv   = tid >> 6;
  const int wr   = wv >> 2;            // 0..1  (M group, 128 rows)
  const int wc   = wv & 3;             // 0..3  (N group, 64 cols)

  // bijective XCD remap
  const int bi     = blockIdx.x;
  const int b      = ((bi & 7) << 1) | ((bi >> 7) & 1);
  const int hwBase = ((bi >> 3) & 15) << 8;

  // ---- staging precompute (2 x 16B loads per thread per half-tile)
  const int row0 = tid >> 3;                    // 0..63
  const int c8   = (tid & 7) ^ (row0 & 7);      // pre-swizzled 16B-chunk col
  const long aOff0 = (long)row0*KKTOT + c8*8;
  const long aOff1 = aOff0 + (long)64*KKTOT;
  const int x  = row0;
  const int y0 = hwBase >> 6;
  long bOff[2][2];
  #pragma unroll
  for (int h = 0; h < 2; ++h)
    #pragma unroll
    for (int l = 0; l < 2; ++l)
      bOff[h][l] = (((long)b*HP + y0 + 2*h + l)*HP + x)*IC + c8*8;
  const unsigned wvOff = wv << 10;

#define STAGE_A(tt, h) do {                                              \
    char* d_ = ldsc + (((tt)&1)<<16) + ((h)<<14) + wvOff;                \
    const __bf16* g_ = wmat + (h)*(128*KKTOT) + (tt)*64;                 \
    gl2lds16(g_ + aOff0, d_);                                            \
    gl2lds16(g_ + aOff1, d_ + 8192);                                     \
  } while (0)

#define STAGE_B(tt, h, sb) do {                                          \
    char* d_ = ldsc + (((tt)&1)<<16) + 32768 + ((h)<<14) + wvOff;        \
    gl2lds16(xt + bOff[h][0] + (sb), d_);                                 \
    gl2lds16(xt + bOff[h][1] + (sb), d_ + 8192);                          \
  } while (0)

  // ---- prologue: tile 0 (parity 0), sb=0
  STAGE_A(0, 0); STAGE_A(0, 1);
  STAGE_B(0, 0, 0); STAGE_B(0, 1, 0);
  __syncthreads();

  f32x4 acc[8][4] = {};
  bf16x8 af0[2][2], af1[2][2];   // ping-pong A quadrant sets (static idx)
  bf16x8 bfr[4][2];
  const int cb = (lane >> 4) << 4;
  const int rA = wr*128 + (lane & 15);
  const int rB = wc*64  + (lane & 15);

#define READ_A_TO(AF, q) do {                                            \
    _Pragma("unroll")                                                    \
    for (int m2 = 0; m2 < 2; ++m2) {                                     \
      int rr = rA + (q)*32 + m2*16, sw = (rr & 7) << 4;                  \
      AF[m2][0] = *(const bf16x8*)(Abuf + rr*128 + ((  0 + cb) ^ sw));   \
      AF[m2][1] = *(const bf16x8*)(Abuf + rr*128 + (( 64 + cb) ^ sw));   \
    }                                                                    \
  } while (0)

// T19: request emission order {1 DS_READ, 4 MFMA} x4 within this region so
// the following quadrant's frag reads interleave into this MFMA cluster.
#define SGB_INTERLEAVE() do {                                            \
    _Pragma("unroll")                                                    \
    for (int g_ = 0; g_ < 4; ++g_) {                                     \
      __builtin_amdgcn_sched_group_barrier(0x100, 1, 0);                 \
      __builtin_amdgcn_sched_group_barrier(0x008, 4, 0);                 \
    }                                                                    \
  } while (0)

#define MFMA_Q(q, AF, SGB) do {                                          \
    __builtin_amdgcn_s_setprio(1);                                       \
    if (SGB) SGB_INTERLEAVE();                                           \
    _Pragma("unroll")                                                    \
    for (int ks = 0; ks < 2; ++ks)                                       \
      _Pragma("unroll")                                                  \
      for (int m2 = 0; m2 < 2; ++m2)                                     \
        _Pragma("unroll")                                                \
        for (int n = 0; n < 4; ++n)                                      \
          acc[(q)*2+m2][n] = __builtin_amdgcn_mfma_f32_16x16x32_bf16(AF[m2][ks], bfr[n][ks], acc[(q)*2+m2][n], 0, 0, 0); \
    __builtin_amdgcn_s_setprio(0);                                       \
  } while (0)

  for (int t = 0; t < 36; ++t) {
    char* Abuf = ldsc + ((t & 1) << 16);
    char* Bbuf = Abuf + 32768;
    const int tt = t + 1, pos = tt >> 2, kh = pos/3;
    const int sb1 = (kh*HP + (pos - kh*3))*IC + ((tt & 3) << 6);

    // tile-start reads: B frags + A[q0]; A[q1] one ahead
    #pragma unroll
    for (int n = 0; n < 4; ++n) {
      int rr = rB + n*16, sw = (rr & 7) << 4;
      bfr[n][0] = *(const bf16x8*)(Bbuf + rr*128 + ((  0 + cb) ^ sw));
      bfr[n][1] = *(const bf16x8*)(Bbuf + rr*128 + (( 64 + cb) ^ sw));
    }
    READ_A_TO(af0, 0);
    READ_A_TO(af1, 1);
    if (t < 35) { STAGE_A(tt, 0); STAGE_B(tt, 0, sb1); }

    MFMA_Q(0, af0, 1);              // SGB pulls the q2 reads into this cluster
    READ_A_TO(af0, 2);
    if (t < 35) { STAGE_A(tt, 1); STAGE_B(tt, 1, sb1); }

    MFMA_Q(1, af1, 1);              // SGB pulls the q3 reads into this cluster
    READ_A_TO(af1, 3);

    MFMA_Q(2, af0, 0);
    MFMA_Q(3, af1, 0);

    __syncthreads();                // single sync: fence + barrier + drains
  }

  // ---- epilogue: f32 stores, 16-lane 64B segments
  float* outb = out + (((long)b*OC + wr*128 + ((lane >> 4) << 2))*(Hh*Ww))
                    + hwBase + wc*64 + (lane & 15);
  #pragma unroll
  for (int m = 0; m < 8; ++m)
    #pragma unroll
    for (int n = 0; n < 4; ++n)
      #pragma unroll
      for (int j = 0; j < 4; ++j)
        outb[((long)(m*16 + j))*(Hh*Ww) + n*16] = acc[m][n][j];
}

extern "C" void kernel_launch(void* const* d_in, const int* in_sizes, int n_in,
                              void* d_out, int out_size, void* d_ws, size_t ws_size,
                              hipStream_t stream) {
  const float* image = (const float*)d_in[0];
  const float* style = (const float*)d_in[1];
  const float* weight= (const float*)d_in[2];
  const float* modw  = (const float*)d_in[3];
  float* out = (float*)d_out;

  char* ws = (char*)d_ws;
  __bf16* xt   = (__bf16*)ws;
  __bf16* wmat = (__bf16*)(ws + WMAT_OFF);
  float*  sbuf = (float*)(ws + S_OFF);

  k_prep<<<272, 256, 0, stream>>>(weight, style, modw, wmat, sbuf);
  k_xmod<<<Bb*256 + Bb, 256, 0, stream>>>(image, sbuf, xt);
  k_conv<<<256, 512, 0, stream>>>(wmat, xt, out);
}

// Round 12
// 105.692 us; speedup vs baseline: 1.1092x; 1.0013x over previous
//
#include <hip/hip_runtime.h>

typedef __bf16 bf16x8 __attribute__((ext_vector_type(8)));
typedef float  f32x4  __attribute__((ext_vector_type(4)));

#define IC    256
#define OC    256
#define Hh    64
#define Ww    64
#define Bb    16
#define DLEN  512
#define KKTOT 2304        // IC*9
#define HP    66          // padded spatial
#define MODSCALE 0.0625f                 // sqrt(2/512)
#define WSCALE   0.029462782549439484f   // sqrt(2/2304)

// workspace layout (bytes)
#define XT_ELEMS  (Bb*HP*HP*IC)          // 17,842,176 bf16
#define XT_BYTES  (XT_ELEMS*2)           // 35,684,352
#define WMAT_OFF  XT_BYTES
#define WMAT_BYTES (OC*KKTOT*2)          // 1,179,648
#define S_OFF     (WMAT_OFF + WMAT_BYTES)

typedef const __attribute__((address_space(1))) unsigned int* gptr_t;
typedef __attribute__((address_space(3))) unsigned int* lptr_t;

__device__ __forceinline__ void gl2lds16(const void* g, void* l) {
  __builtin_amdgcn_global_load_lds((gptr_t)g, (lptr_t)l, 16, 0, 0);
}

// ---------------- merged prep: blocks 0..255 = wmat(+demod), 256..271 = style
__global__ void k_prep(const float* __restrict__ wt,
                       const float* __restrict__ style,
                       const float* __restrict__ mw,
                       __bf16* __restrict__ wmat,
                       float* __restrict__ s_out) {
  const int t = threadIdx.x;
  if (blockIdx.x >= 256) {
    const int b = blockIdx.x - 256;
    __shared__ float st[DLEN];
    st[t]       = style[b*DLEN + t];
    st[t + 256] = style[b*DLEN + t + 256];
    __syncthreads();
    const float4* mwr = (const float4*)(mw + (long)t*DLEN);
    float acc = 0.f;
    #pragma unroll 4
    for (int d = 0; d < DLEN/4; ++d) {
      float4 v = mwr[d];
      acc += v.x*st[d*4] + v.y*st[d*4+1] + v.z*st[d*4+2] + v.w*st[d*4+3];
    }
    s_out[b*IC + t] = acc * MODSCALE;
    return;
  }
  const int oc = blockIdx.x;
  float w9[9];
  const float* p = wt + ((long)oc*IC + t)*9;
  float ss = 0.f;
  #pragma unroll
  for (int r = 0; r < 9; ++r) { w9[r] = p[r]; ss += w9[r]*w9[r]; }
  #pragma unroll
  for (int off = 32; off; off >>= 1) ss += __shfl_down(ss, off, 64);
  __shared__ float red[4];
  if ((t & 63) == 0) red[t >> 6] = ss;
  __syncthreads();
  float total = red[0] + red[1] + red[2] + red[3];
  float dm = WSCALE / sqrtf(total + 1e-8f);
  #pragma unroll
  for (int r = 0; r < 9; ++r)
    wmat[oc*KKTOT + r*IC + t] = (__bf16)(w9[r] * dm);
}

// ---------------- xt[b][y+1][x+1][ic] = bf16(image[b][ic][y][x] * s[b][ic]) (NHWC, padded)
// blocks >= Bb*256 zero the halo of batch (blockIdx.x - Bb*256); writes disjoint.
__global__ void k_xmod(const float* __restrict__ img,
                       const float* __restrict__ s,
                       __bf16* __restrict__ xt) {
  const int t = threadIdx.x;
  if (blockIdx.x >= Bb*256) {
    const int b = blockIdx.x - Bb*256;
    uint4* base = (uint4*)(xt + (long)b*HP*HP*IC);
    const uint4 z = {0u,0u,0u,0u};
    for (int i = t; i < 2112; i += 256) { base[i] = z; base[137280 + i] = z; }
    for (int i = t; i < 64*32; i += 256) {
      int y = 1 + (i >> 5), c = i & 31;
      base[y*2112 + c] = z;
      base[y*2112 + 2080 + c] = z;
    }
    return;
  }
  __shared__ float tile[64][69];
  const int b   = blockIdx.x >> 8;
  const int rem = blockIdx.x & 255;
  const int y   = rem >> 2;          // source row 0..63
  const int ic0 = (rem & 3) << 6;    // ic block of 64
  #pragma unroll
  for (int r = 0; r < 4; ++r) {
    int seg = r*256 + t;
    int i   = seg >> 4;              // ic offset 0..63
    int x0  = (seg & 15) * 4;
    float4 v = *(const float4*)(img + (((long)(b*IC + ic0 + i)*Hh + y)*Ww + x0));
    float sv = s[b*IC + ic0 + i];
    tile[i][x0+0] = v.x*sv; tile[i][x0+1] = v.y*sv;
    tile[i][x0+2] = v.z*sv; tile[i][x0+3] = v.w*sv;
  }
  __syncthreads();
  const int x  = t >> 2;
  const int j0 = (t & 3) << 4;
  bf16x8 o0, o1;
  #pragma unroll
  for (int e = 0; e < 8; ++e) o0[e] = (__bf16)tile[j0 + e][x];
  #pragma unroll
  for (int e = 0; e < 8; ++e) o1[e] = (__bf16)tile[j0 + 8 + e][x];
  __bf16* dst = xt + (((long)(b*HP + y + 1)*HP + (x + 1))*IC + ic0 + j0);
  ((bf16x8*)dst)[0] = o0;
  ((bf16x8*)dst)[1] = o1;
}

// ---------------- 256x256x64 implicit-GEMM conv: single __syncthreads/tile
// (proven 75us structure) with COLUMN-PAIR phase decomposition: 4 clusters of
// 16 MFMA (8m x 2n x 1ks), each preceded only by its incremental ds_reads
// (10/2/10/2 instead of 20 bunched at tile start), staging interleaved.
__global__ __launch_bounds__(512, 2) void k_conv(const __bf16* __restrict__ wmat,
                                                 const __bf16* __restrict__ xt,
                                                 float* __restrict__ out) {
  __shared__ __attribute__((aligned(128))) char ldsc[131072]; // 2 bufs x (A 32K | B 32K)
  const int tid  = threadIdx.x;
  const int lane = tid & 63;
  const int wv   = tid >> 6;
  const int wr   = wv >> 2;            // 0..1  (M group, 128 rows)
  const int wc   = wv & 3;             // 0..3  (N group, 64 cols)

  // bijective XCD remap
  const int bi     = blockIdx.x;
  const int b      = ((bi & 7) << 1) | ((bi >> 7) & 1);
  const int hwBase = ((bi >> 3) & 15) << 8;

  // ---- staging precompute (2 x 16B loads per thread per half-tile)
  const int row0 = tid >> 3;                    // 0..63
  const int c8   = (tid & 7) ^ (row0 & 7);      // pre-swizzled 16B-chunk col
  const long aOff0 = (long)row0*KKTOT + c8*8;
  const long aOff1 = aOff0 + (long)64*KKTOT;
  const int x  = row0;
  const int y0 = hwBase >> 6;
  long bOff[2][2];
  #pragma unroll
  for (int h = 0; h < 2; ++h)
    #pragma unroll
    for (int l = 0; l < 2; ++l)
      bOff[h][l] = (((long)b*HP + y0 + 2*h + l)*HP + x)*IC + c8*8;
  const unsigned wvOff = wv << 10;

#define STAGE_A(tt, h) do {                                              \
    char* d_ = ldsc + (((tt)&1)<<16) + ((h)<<14) + wvOff;                \
    const __bf16* g_ = wmat + (h)*(128*KKTOT) + (tt)*64;                 \
    gl2lds16(g_ + aOff0, d_);                                            \
    gl2lds16(g_ + aOff1, d_ + 8192);                                     \
  } while (0)

#define STAGE_B(tt, h, sb) do {                                          \
    char* d_ = ldsc + (((tt)&1)<<16) + 32768 + ((h)<<14) + wvOff;        \
    gl2lds16(xt + bOff[h][0] + (sb), d_);                                 \
    gl2lds16(xt + bOff[h][1] + (sb), d_ + 8192);                          \
  } while (0)

  // ---- prologue: tile 0 (parity 0), sb=0
  STAGE_A(0, 0); STAGE_A(0, 1);
  STAGE_B(0, 0, 0); STAGE_B(0, 1, 0);
  __syncthreads();

  f32x4 acc[8][4] = {};
  bf16x8 af0[8], af1[8];         // A frags for ks0 / ks1 (named sets, no WAR)
  bf16x8 bfr[4][2];              // B frags [n][ks]
  const int cb = (lane >> 4) << 4;
  const int rA = wr*128 + (lane & 15);
  const int rB = wc*64  + (lane & 15);

// read the 8 A frags for one ks column
#define READ_A8(AF, ks) do {                                             \
    _Pragma("unroll")                                                    \
    for (int m = 0; m < 8; ++m) {                                        \
      int rr = rA + m*16, sw = (rr & 7) << 4;                            \
      AF[m] = *(const bf16x8*)(Abuf + rr*128 + (((ks)*64 + cb) ^ sw));   \
    }                                                                    \
  } while (0)

// read one n-pair of B frags for one ks column
#define READ_B2(np, ks) do {                                             \
    _Pragma("unroll")                                                    \
    for (int n = 2*(np); n < 2*(np)+2; ++n) {                            \
      int rr = rB + n*16, sw = (rr & 7) << 4;                            \
      bfr[n][ks] = *(const bf16x8*)(Bbuf + rr*128 + (((ks)*64 + cb) ^ sw)); \
    }                                                                    \
  } while (0)

// 16 MFMA: all m x one n-pair x one ks
#define MFMA_PAIR(np, ks, AF) do {                                       \
    __builtin_amdgcn_s_setprio(1);                                       \
    _Pragma("unroll")                                                    \
    for (int m = 0; m < 8; ++m)                                          \
      _Pragma("unroll")                                                  \
      for (int n = 2*(np); n < 2*(np)+2; ++n)                            \
        acc[m][n] = __builtin_amdgcn_mfma_f32_16x16x32_bf16(AF[m], bfr[n][ks], acc[m][n], 0, 0, 0); \
    __builtin_amdgcn_s_setprio(0);                                       \
  } while (0)

  for (int t = 0; t < 36; ++t) {
    char* Abuf = ldsc + ((t & 1) << 16);
    char* Bbuf = Abuf + 32768;
    const int tt = t + 1, pos = tt >> 2, kh = pos/3;
    const int sb1 = (kh*HP + (pos - kh*3))*IC + ((tt & 3) << 6);

    READ_A8(af0, 0);
    READ_B2(0, 0);
    if (t < 35) STAGE_A(tt, 0);
    MFMA_PAIR(0, 0, af0);

    READ_B2(1, 0);
    if (t < 35) STAGE_A(tt, 1);
    MFMA_PAIR(1, 0, af0);

    READ_A8(af1, 1);
    READ_B2(0, 1);
    if (t < 35) STAGE_B(tt, 0, sb1);
    MFMA_PAIR(0, 1, af1);

    READ_B2(1, 1);
    if (t < 35) STAGE_B(tt, 1, sb1);
    MFMA_PAIR(1, 1, af1);

    __syncthreads();                // single sync: fence + barrier + drains
  }

  // ---- epilogue: f32 stores, 16-lane 64B segments
  float* outb = out + (((long)b*OC + wr*128 + ((lane >> 4) << 2))*(Hh*Ww))
                    + hwBase + wc*64 + (lane & 15);
  #pragma unroll
  for (int m = 0; m < 8; ++m)
    #pragma unroll
    for (int n = 0; n < 4; ++n)
      #pragma unroll
      for (int j = 0; j < 4; ++j)
        outb[((long)(m*16 + j))*(Hh*Ww) + n*16] = acc[m][n][j];
}

extern "C" void kernel_launch(void* const* d_in, const int* in_sizes, int n_in,
                              void* d_out, int out_size, void* d_ws, size_t ws_size,
                              hipStream_t stream) {
  const float* image = (const float*)d_in[0];
  const float* style = (const float*)d_in[1];
  const float* weight= (const float*)d_in[2];
  const float* modw  = (const float*)d_in[3];
  float* out = (float*)d_out;

  char* ws = (char*)d_ws;
  __bf16* xt   = (__bf16*)ws;
  __bf16* wmat = (__bf16*)(ws + WMAT_OFF);
  float*  sbuf = (float*)(ws + S_OFF);

  k_prep<<<272, 256, 0, stream>>>(weight, style, modw, wmat, sbuf);
  k_xmod<<<Bb*256 + Bb, 256, 0, stream>>>(image, sbuf, xt);
  k_conv<<<256, 512, 0, stream>>>(wmat, xt, out);
}